// Round 5
// baseline (99.282 us; speedup 1.0000x reference)
//
#include <hip/hip_runtime.h>
#include <hip/hip_bf16.h>

// B=8, C=64, O=64, H=W=128, stride=1, pad=1, 3x3.
constexpr int Bc = 8;
constexpr int Cc = 64;
constexpr int Oc = 64;
constexpr int Hc = 128;
constexpr int Wc = 128;
constexpr int HWc = Hc * Wc;
constexpr int CP = 72;   // padded LDS row stride bf16 (144 B = 16B-aligned)

typedef __attribute__((ext_vector_type(8))) short short8;   // 8 x bf16
typedef __attribute__((ext_vector_type(4))) float floatx4;
typedef __attribute__((ext_vector_type(2))) float floatx2;

__device__ __forceinline__ float bperm(int idx4, float v) {
    return __int_as_float(__builtin_amdgcn_ds_bpermute(idx4, __float_as_int(v)));
}
// packed f32x2 -> bf16x2 (RNE), lo -> bits[15:0]
__device__ __forceinline__ unsigned cvt_pk_bf16(float lo, float hi) {
    unsigned r;
    asm("v_cvt_pk_bf16_f32 %0, %1, %2" : "=v"(r) : "v"(lo), "v"(hi));
    return r;
}

// v6 = v5 (2-row blocks, float2 lanes, bpermute horizontal taps) restructured
// for latency, not instruction count (v5 post-mortem: VMEM dieting elasticity
// ~0.3; kernel is exposed-latency + barrier-convoy bound):
//  - Phase 0 deleted: A-fragments loaded per-wave directly from global core
//    (L2-hot 16KB), issued FIRST, consumed in Phase 3 -> no serial staging.
//  - All 32 tap loads hoisted ahead of all compute (full unroll, static
//    indices): MLP 16 -> 32 in flight, exposed latency ~halved.
//  - Barrier 2 removed from common path: every wave redundantly reduces the
//    div partials for all 256 pixels (conflict-free LDS reads) and computes
//    a wave-uniform __any(bad); mask-clean blocks (the measure-1 case) go
//    straight to GEMM after the single barrier. Rare path fully barriered.
__global__ __launch_bounds__(512, 4) void spconv_kernel(
    const float* __restrict__ x, const float* __restrict__ core,
    const float* __restrict__ peri, const float* __restrict__ thr,
    const float* __restrict__ scl, float* __restrict__ out)
{
    __shared__ __hip_bfloat16 s_selT[2][Wc][CP];  // [row][physw][c] 36864 B
    __shared__ float s_divp[2][8][Wc];            //                  8192 B
    __shared__ float s_msk[2][Wc];                // rare path only   1024 B

    const int tid = threadIdx.x;
    const int l   = tid & 63;                   // lane
    const int wv  = tid >> 6;                   // wave 0..7
    const int b   = blockIdx.x & 7;             // one image per XCD
    const int hp  = blockIdx.x >> 3;            // row pair 0..63
    const int h0  = hp * 2;

    // GEMM geometry (needed for A-fragment addresses)
    const int o0   = (wv & 3) * 16;
    const int wh   = wv >> 2;
    const int n    = l & 15;
    const int quad = l >> 4;

    // ---- A-fragment loads FIRST: in flight through all of phase 1 ----
    const float* arow = core + (size_t)(o0 + n) * Cc + quad * 8;
    const floatx4 af0 = *(const floatx4*)(arow);        // k 0..3
    const floatx4 af1 = *(const floatx4*)(arow + 4);    // k 4..7
    const floatx4 af2 = *(const floatx4*)(arow + 32);   // k 32..35
    const floatx4 af3 = *(const floatx4*)(arow + 36);   // k 36..39

    // ---- Phase 1 tap loads: ALL hoisted (32 float2, static indices) ----
    const int   dU  = (h0 > 0) ? -Wc : 0;          // clamped row offsets
    const int   dD2 = (h0 < Hc - 2) ? 2 * Wc : Wc;
    const float* xw = x + (size_t)b * Cc * HWc + (size_t)h0 * Wc + 2 * l;
    const float* xb = x + (size_t)b * Cc * HWc + (size_t)h0 * Wc;

    floatx2 R[4][8];
    #pragma unroll
    for (int j = 0; j < 4; ++j) {
        const float* b0p = xw + (size_t)(wv * 8 + 2 * j) * HWc;
        const float* b1p = b0p + HWc;
        R[j][0] = *(const floatx2*)(b0p + dU);
        R[j][1] = *(const floatx2*)(b0p);
        R[j][2] = *(const floatx2*)(b0p + Wc);
        R[j][3] = *(const floatx2*)(b0p + dD2);
        R[j][4] = *(const floatx2*)(b1p + dU);
        R[j][5] = *(const floatx2*)(b1p);
        R[j][6] = *(const floatx2*)(b1p + Wc);
        R[j][7] = *(const floatx2*)(b1p + dD2);
    }

    // ---- pack A-fragments (waits only on the first 4 loads) ----
    union { unsigned u[4]; short8 s; } A0, A1;
    A0.u[0] = cvt_pk_bf16(af0.x, af0.y); A0.u[1] = cvt_pk_bf16(af0.z, af0.w);
    A0.u[2] = cvt_pk_bf16(af1.x, af1.y); A0.u[3] = cvt_pk_bf16(af1.z, af1.w);
    A1.u[0] = cvt_pk_bf16(af2.x, af2.y); A1.u[1] = cvt_pk_bf16(af2.z, af2.w);
    A1.u[2] = cvt_pk_bf16(af3.x, af3.y); A1.u[3] = cvt_pk_bf16(af3.z, af3.w);

    // ---- Phase 1 compute ----
    const int upIdx = ((l - 1) & 63) << 2;      // bperm byte idx: lane l-1
    const int dnIdx = ((l + 1) & 63) << 2;      // lane l+1
    const float lzf = (l == 0)  ? 0.f : 1.f;    // w=0 left pad
    const float rzf = (l == 63) ? 0.f : 1.f;    // w=127 right pad
    const float mUf = (h0 > 0) ? 1.f : 0.f;
    const float mDf = (h0 < Hc - 2) ? 1.f : 0.f;

    const float p0 = peri[0], p1 = peri[1], p2 = peri[2], p3 = peri[3];
    const float p4 = peri[4], p5 = peri[5], p6 = peri[6], p7 = peri[7];
    const float thrv = thr[0], sclv = scl[0];

    float dAlo = 0.f, dAhi = 0.f, dBlo = 0.f, dBhi = 0.f;

#define PROC(RM, R0, R1, R2, K) do {                                          \
    const float rmL = lzf * bperm(upIdx, RM.y);                               \
    const float r0L = lzf * bperm(upIdx, R0.y);                               \
    const float r1L = lzf * bperm(upIdx, R1.y);                               \
    const float r2L = lzf * bperm(upIdx, R2.y);                               \
    const float rmR = rzf * bperm(dnIdx, RM.x);                               \
    const float r0R = rzf * bperm(dnIdx, R0.x);                               \
    const float r1R = rzf * bperm(dnIdx, R1.x);                               \
    const float r2R = rzf * bperm(dnIdx, R2.x);                               \
    { const float t = R0.x;  /* row A, pixel lo (w=2l) */                     \
      float a = p0 * rmL; a = fmaf(p1, RM.x, a); a = fmaf(p2, RM.y, a);       \
      a = fmaf(p3, r0L, a); a = fmaf(p4, R0.y, a);                            \
      a = fmaf(p5, r1L, a); a = fmaf(p6, R1.x, a); a = fmaf(p7, R1.y, a);     \
      aAlo[K] = a; float e;                                                   \
      e = rmL  - t; dAlo = fmaf(e, e, dAlo); e = RM.x - t; dAlo = fmaf(e, e, dAlo); \
      e = RM.y - t; dAlo = fmaf(e, e, dAlo); e = r0L  - t; dAlo = fmaf(e, e, dAlo); \
      e = R0.y - t; dAlo = fmaf(e, e, dAlo); e = r1L  - t; dAlo = fmaf(e, e, dAlo); \
      e = R1.x - t; dAlo = fmaf(e, e, dAlo); e = R1.y - t; dAlo = fmaf(e, e, dAlo); } \
    { const float t = R0.y;  /* row A, pixel hi (w=2l+1) */                   \
      float a = p0 * RM.x; a = fmaf(p1, RM.y, a); a = fmaf(p2, rmR, a);       \
      a = fmaf(p3, R0.x, a); a = fmaf(p4, r0R, a);                            \
      a = fmaf(p5, R1.x, a); a = fmaf(p6, R1.y, a); a = fmaf(p7, r1R, a);     \
      aAhi[K] = a; float e;                                                   \
      e = RM.x - t; dAhi = fmaf(e, e, dAhi); e = RM.y - t; dAhi = fmaf(e, e, dAhi); \
      e = rmR  - t; dAhi = fmaf(e, e, dAhi); e = R0.x - t; dAhi = fmaf(e, e, dAhi); \
      e = r0R  - t; dAhi = fmaf(e, e, dAhi); e = R1.x - t; dAhi = fmaf(e, e, dAhi); \
      e = R1.y - t; dAhi = fmaf(e, e, dAhi); e = r1R  - t; dAhi = fmaf(e, e, dAhi); } \
    { const float t = R1.x;  /* row B, pixel lo */                            \
      float a = p0 * r0L; a = fmaf(p1, R0.x, a); a = fmaf(p2, R0.y, a);       \
      a = fmaf(p3, r1L, a); a = fmaf(p4, R1.y, a);                            \
      a = fmaf(p5, r2L, a); a = fmaf(p6, R2.x, a); a = fmaf(p7, R2.y, a);     \
      aBlo[K] = a; float e;                                                   \
      e = r0L  - t; dBlo = fmaf(e, e, dBlo); e = R0.x - t; dBlo = fmaf(e, e, dBlo); \
      e = R0.y - t; dBlo = fmaf(e, e, dBlo); e = r1L  - t; dBlo = fmaf(e, e, dBlo); \
      e = R1.y - t; dBlo = fmaf(e, e, dBlo); e = r2L  - t; dBlo = fmaf(e, e, dBlo); \
      e = R2.x - t; dBlo = fmaf(e, e, dBlo); e = R2.y - t; dBlo = fmaf(e, e, dBlo); } \
    { const float t = R1.y;  /* row B, pixel hi */                            \
      float a = p0 * R0.x; a = fmaf(p1, R0.y, a); a = fmaf(p2, r0R, a);       \
      a = fmaf(p3, R1.x, a); a = fmaf(p4, r1R, a);                            \
      a = fmaf(p5, R2.x, a); a = fmaf(p6, R2.y, a); a = fmaf(p7, r2R, a);     \
      aBhi[K] = a; float e;                                                   \
      e = R0.x - t; dBhi = fmaf(e, e, dBhi); e = R0.y - t; dBhi = fmaf(e, e, dBhi); \
      e = r0R  - t; dBhi = fmaf(e, e, dBhi); e = R1.x - t; dBhi = fmaf(e, e, dBhi); \
      e = r1R  - t; dBhi = fmaf(e, e, dBhi); e = R2.x - t; dBhi = fmaf(e, e, dBhi); \
      e = R2.y - t; dBhi = fmaf(e, e, dBhi); e = r2R  - t; dBhi = fmaf(e, e, dBhi); } \
} while (0)

    #pragma unroll
    for (int j = 0; j < 4; ++j) {
        const int c0 = wv * 8 + 2 * j;
        floatx2 rm0 = R[j][0] * mUf;
        floatx2 r00 = R[j][1];
        floatx2 r10 = R[j][2];
        floatx2 r20 = R[j][3] * mDf;
        floatx2 rm1 = R[j][4] * mUf;
        floatx2 r01 = R[j][5];
        floatx2 r11 = R[j][6];
        floatx2 r21 = R[j][7] * mDf;

        float aAlo[2], aAhi[2], aBlo[2], aBhi[2];
        PROC(rm0, r00, r10, r20, 0);
        PROC(rm1, r01, r11, r21, 1);

        // packed bf16x2 writes; phys rows: w=2l -> l, w=2l+1 -> 64+l
        *(unsigned*)&s_selT[0][l]      [c0] = cvt_pk_bf16(aAlo[0], aAlo[1]);
        *(unsigned*)&s_selT[0][64 + l] [c0] = cvt_pk_bf16(aAhi[0], aAhi[1]);
        *(unsigned*)&s_selT[1][l]      [c0] = cvt_pk_bf16(aBlo[0], aBlo[1]);
        *(unsigned*)&s_selT[1][64 + l] [c0] = cvt_pk_bf16(aBhi[0], aBhi[1]);
    }
#undef PROC

    {   // div partials (logical w indexing)
        floatx2 da = {dAlo, dAhi}, db = {dBlo, dBhi};
        *(floatx2*)&s_divp[0][wv][2 * l] = da;
        *(floatx2*)&s_divp[1][wv][2 * l] = db;
    }
    __syncthreads();        // the ONLY barrier in the common path

    // ---- per-wave redundant mask check (no second barrier needed) ----
    bool bad = false;
    #pragma unroll
    for (int k = 0; k < 4; ++k) {
        const int idx = k * 64 + l;            // 0..255, lane-consecutive
        const int rr = idx >> 7, ww = idx & (Wc - 1);
        float dv = s_divp[rr][0][ww];
        #pragma unroll
        for (int g = 1; g < 8; ++g) dv += s_divp[rr][g][ww];
        bad |= (((dv - thrv) * sclv) <= 0.f);  // !(sigmoid>0.5)
    }
    if (__any(bad)) {
        // ---- rare path: fully barriered fixup ----
        if (tid < 2 * Wc) {
            const int rr = tid >> 7, ww = tid & (Wc - 1);
            float dv = s_divp[rr][0][ww];
            #pragma unroll
            for (int g = 1; g < 8; ++g) dv += s_divp[rr][g][ww];
            s_msk[rr][ww] = (((dv - thrv) * sclv) > 0.f) ? 1.f : 0.f;
        }
        __syncthreads();
        #pragma unroll
        for (int i = 0; i < 32; ++i) {         // 2*8192 elems / 512 thr
            const int idx = i * 512 + tid;
            const int rr  = idx >> 13;
            const int e2  = idx & 8191;
            const int p   = e2 & (Wc - 1);                // phys row
            const int c   = e2 >> 7;
            const int ww  = ((p & 63) << 1) | (p >> 6);   // logical w
            if (s_msk[rr][ww] == 0.f)
                s_selT[rr][p][c] =
                    __float2bfloat16(xb[(size_t)c * HWc + rr * Wc + ww]);
        }
        __syncthreads();
    }

    // ---- Phase 3: MFMA GEMM x2 rows: D[o][w] = core[o][c]*sel[c][w] ----
    float* outb = out + ((size_t)(b * Oc) * Hc + h0) * Wc;

    #pragma unroll
    for (int rr = 0; rr < 2; ++rr) {
        #pragma unroll
        for (int t = 0; t < 4; ++t) {
            const int w0   = (wh * 4 + t) * 16;
            const int wlog = w0 + n;
            const int pr   = ((wlog >> 1) & 63) | ((wlog & 1) << 6);
            const short8 b0 = *(const short8*)&s_selT[rr][pr][quad * 8];
            const short8 b1 = *(const short8*)&s_selT[rr][pr][quad * 8 + 32];
            floatx4 acc = {0.f, 0.f, 0.f, 0.f};
            acc = __builtin_amdgcn_mfma_f32_16x16x32_bf16(A0.s, b0, acc, 0, 0, 0);
            acc = __builtin_amdgcn_mfma_f32_16x16x32_bf16(A1.s, b1, acc, 0, 0, 0);
            #pragma unroll
            for (int r = 0; r < 4; ++r) {
                const int o = o0 + quad * 4 + r;
                outb[(size_t)o * HWc + rr * Wc + w0 + n] = acc[r];
            }
        }
    }
}

extern "C" void kernel_launch(void* const* d_in, const int* in_sizes, int n_in,
                              void* d_out, int out_size, void* d_ws, size_t ws_size,
                              hipStream_t stream) {
    const float* x    = (const float*)d_in[0];
    const float* core = (const float*)d_in[1];
    const float* peri = (const float*)d_in[2];
    const float* thr  = (const float*)d_in[3];
    const float* scl  = (const float*)d_in[4];
    float* out = (float*)d_out;

    spconv_kernel<<<dim3(Bc * Hc / 2), dim3(512), 0, stream>>>(
        x, core, peri, thr, scl, out);
}